// Round 12
// baseline (2422.889 us; speedup 1.0000x reference)
//
#include <hip/hip_runtime.h>
#include <math.h>

#define TPB 256

typedef _Float16 f16;
typedef _Float16 half8 __attribute__((ext_vector_type(8)));
typedef _Float16 f16x2 __attribute__((ext_vector_type(2)));
typedef _Float16 f16x4 __attribute__((ext_vector_type(4)));
typedef float floatx4 __attribute__((ext_vector_type(4)));

static constexpr int CDIM = 512;
static constexpr int HWD = 2304;
static constexpr float ALPHA = 0.05f;
static constexpr float TOLF = 4.608e-4f;   // B*HW*1e-7

enum { EPI_F32 = 0, EPI_F16BIASN = 1, EPI_F16BIASM = 2, EPI_F16 = 3,
       EPI_WTW = 4, EPI_MEANSTD = 5, EPI_FISTA = 6 };

__device__ __forceinline__ bool fista_done(const float* __restrict__ diffArr, int iter) {
    bool done = false;
    for (int j = 0; j < iter; ++j) done = done || (diffArr[j] <= TOLF);
    return done;
}

// async global->LDS, 16B per lane (global_load_lds_dwordx4).
__device__ __forceinline__ void gload_lds(const f16* g, f16* l) {
#if __has_builtin(__builtin_amdgcn_global_load_lds)
    __builtin_amdgcn_global_load_lds(
        (__attribute__((address_space(1))) void*)(g),
        (__attribute__((address_space(3))) void*)(l), 16, 0, 0);
#else
    *(int4*)l = *(const int4*)g;
#endif
}

// counted vmcnt wait (T4)
template<int N> __device__ __forceinline__ void vwait() {
    if constexpr (N == 0)      asm volatile("s_waitcnt vmcnt(0)" ::: "memory");
    else if constexpr (N == 3) asm volatile("s_waitcnt vmcnt(3)" ::: "memory");
    else if constexpr (N == 4) asm volatile("s_waitcnt vmcnt(4)" ::: "memory");
}

// raw s_barrier with compiler memory fences
__device__ __forceinline__ void barrier_f() {
    asm volatile("" ::: "memory");
    __builtin_amdgcn_s_barrier();
    asm volatile("" ::: "memory");
}

// Generic fp16 MFMA GEMM: C[m,n] = sum_k A[m][k]*B[n][k]  (both operands k-contig).
// Block (MF*32)x64, BK=64, 256 threads = 4 waves (2x2); wave tile (MF*16)x32.
// R12: TLP-first tiling — three rounds proved pipeline depth is NOT the constraint
// (1-phase == drain-0 == counted-vmcnt == 41.5us); grid supply is (576 blocks =
// 2.25/CU, 33% tail imbalance). MF=1 (32x64) for M=1024 GEMMs -> grid 1152
// (4.5 blocks/CU, ~18 waves/CU); MF=2 for 2304-row GEMMs -> grid 1296.
// NBUF=2, counted vmcnt(LCNT): tile t+1's loads stay in flight across the barrier.
// MF changes only which wave computes an output, not its K-accumulation sequence
// -> bit-identical numerics vs R11 (absmax must stay 0.0625).
template<int EPI, int MF>
__global__ __launch_bounds__(TPB, 4) void sgemm(
    const f16* __restrict__ A, long a_bs, int lda,
    const f16* __restrict__ B, long b_bs, int ldb,
    void* __restrict__ C0, long c_bs, int ldc,
    void* __restrict__ C1,
    int K,
    const float* __restrict__ bias,
    const float* __restrict__ xAf,
    float* __restrict__ zc, float* __restrict__ zp, f16* __restrict__ yhp,
    const float* __restrict__ lrs, float coefPrev, float coefCur,
    float* __restrict__ diffArr, int iter)
{
    if (EPI == EPI_FISTA) {
        if (iter > 0 && fista_done(diffArr, iter)) return;
    }
    constexpr int ASZ = MF * 32 * 64;
    constexpr int BSZ = 64 * 64;
    constexpr int LCNT = MF + 2;                // gload_lds ops per STAGE per thread
    __shared__ alignas(16) f16 As[2 * ASZ];
    __shared__ alignas(16) f16 Bs[2 * BSZ];
    const int tid = threadIdx.x;
    const int wid = tid >> 6, lane = tid & 63;
    const int wr = wid >> 1, wc = wid & 1;

    // ---- XCD-aware bijective remap of (bx, by) ----
    const int gx = gridDim.x, gy = gridDim.y;
    const int nwg = gx * gy;
    const int d = blockIdx.y * gx + blockIdx.x;
    const int q = nwg >> 3, r = nwg & 7;
    const int xcd = d & 7, rest = d >> 3;
    const int wgid = (xcd < r ? xcd * (q + 1) : r * (q + 1) + (xcd - r) * q) + rest;
    const int bx = wgid / gy, by = wgid % gy;

    const int m0 = by * (MF * 32), n0 = bx << 6;
    const f16* Ab = A + (long)blockIdx.z * a_bs;
    const f16* Bb = B + (long)blockIdx.z * b_bs;

    floatx4 acc[MF][2] = {};
    floatx4 acc2[MF][2] = {};   // only used by MEANSTD (DCE'd otherwise)

    const int rl = lane & 15, kg = lane >> 4;
    const int lrow = lane >> 3;                 // row-in-chunk
    const int gs = (lane & 7) ^ lrow;           // pre-swizzled global k-chunk

    const int nt = K >> 6;

    // stage K-tile t into LDS buffer buf (async; completion tracked by vmcnt only)
    auto STAGE = [&](int t, int buf) {
        const long k0 = (long)t << 6;
        f16* Ad = As + buf * ASZ;
        f16* Bd = Bs + buf * BSZ;
        #pragma unroll
        for (int p = 0; p < MF; ++p) {
            const int c = wid * MF + p;
            const int R = c * 8 + lrow;
            gload_lds(Ab + (long)(m0 + R) * lda + k0 + gs * 8, Ad + c * 512);
        }
        #pragma unroll
        for (int p = 0; p < 2; ++p) {
            const int c = wid * 2 + p;
            const int R = c * 8 + lrow;
            gload_lds(Bb + (long)(n0 + R) * ldb + k0 + gs * 8, Bd + c * 512);
        }
    };

    STAGE(0, 0);
    for (int t = 0; t < nt; ++t) {
        if (t + 1 < nt) {
            STAGE(t + 1, (t + 1) & 1);
            vwait<LCNT>();                      // tile t done; t+1's loads stay in flight
        } else {
            vwait<0>();
        }
        barrier_f();                            // tile t published block-wide
        const f16* Ac = As + (t & 1) * ASZ;
        const f16* Bc = Bs + (t & 1) * BSZ;
        #pragma unroll
        for (int kk = 0; kk < 2; ++kk) {
            const int j = kk * 4 + kg;
            half8 af[MF], bf[2];
            #pragma unroll
            for (int f = 0; f < MF; ++f) {
                const int rowa = wr * (MF * 16) + f * 16 + rl;
                af[f] = *(const half8*)&Ac[rowa * 64 + ((j ^ (rowa & 7)) * 8)];
            }
            #pragma unroll
            for (int f = 0; f < 2; ++f) {
                const int rowb = wc * 32 + f * 16 + rl;
                bf[f] = *(const half8*)&Bc[rowb * 64 + ((j ^ (rowb & 7)) * 8)];
            }
            #pragma unroll
            for (int fi = 0; fi < MF; ++fi) {
                #pragma unroll
                for (int fj = 0; fj < 2; ++fj) {
                    acc[fi][fj] = __builtin_amdgcn_mfma_f32_16x16x32_f16(af[fi], bf[fj], acc[fi][fj], 0, 0, 0);
                    if constexpr (EPI == EPI_MEANSTD) {
                        half8 bq = bf[fj] * bf[fj];
                        acc2[fi][fj] = __builtin_amdgcn_mfma_f32_16x16x32_f16(af[fi], bq, acc2[fi][fj], 0, 0, 0);
                    }
                }
            }
        }
        barrier_f();   // all waves done reading buf (t&1) -> safe STAGE target next iter
    }

    const int rg = lane >> 4;
    const int bz = blockIdx.z;
    float loc = 0.f;
    float lr = 0.f, sh = 0.f;
    if constexpr (EPI == EPI_FISTA) { lr = lrs[0]; sh = lrs[1]; }

    #pragma unroll
    for (int fi = 0; fi < MF; ++fi) {
        #pragma unroll
        for (int fj = 0; fj < 2; ++fj) {
            #pragma unroll
            for (int r2 = 0; r2 < 4; ++r2) {
                const int row = m0 + wr * (MF * 16) + fi * 16 + rg * 4 + r2;
                const int col = n0 + wc * 32 + fj * 16 + rl;
                const float v = acc[fi][fj][r2];
                if constexpr (EPI == EPI_F32) {
                    ((float*)C0)[bz * c_bs + (long)row * ldc + col] = v;
                } else if constexpr (EPI == EPI_F16BIASN) {
                    ((f16*)C0)[bz * c_bs + (long)row * ldc + col] = (f16)(v + bias[col]);
                } else if constexpr (EPI == EPI_F16BIASM) {
                    ((f16*)C0)[bz * c_bs + (long)row * ldc + col] = (f16)(v + bias[row]);
                } else if constexpr (EPI == EPI_F16) {
                    ((f16*)C0)[bz * c_bs + (long)row * ldc + col] = (f16)v;
                } else if constexpr (EPI == EPI_WTW) {
                    ((float*)C0)[(long)row * ldc + col] = v;
                    ((f16*)C1)[(long)row * ldc + col] = (f16)v;
                } else if constexpr (EPI == EPI_MEANSTD) {
                    const float m_ = v;
                    float s2 = acc2[fi][fj][r2] - m_ * m_;
                    const long o = ((long)bz * CDIM + col) * HWD + row;
                    ((f16*)C0)[o] = (f16)m_;
                    ((f16*)C1)[o] = (f16)sqrtf(s2 > 0.f ? s2 : 0.f);
                } else {  // EPI_FISTA
                    const long off = (long)row * HWD + col;
                    const float zk = zc[off];
                    const float zkm = zp[off];
                    const float ykf = zk + coefPrev * (zk - zkm);
                    const float grad = v - xAf[off];
                    const float p = ykf - lr * grad;
                    const float ap = fabsf(p) - sh;
                    const float zn = ap > 0.f ? copysignf(ap, p) : 0.f;
                    zp[off] = zn;                       // z_{k+1} into old z_{k-1} slot
                    yhp[off] = (f16)(zn + coefCur * (zn - zk));
                    loc += fabsf(zn - zk);
                }
            }
        }
    }
    if constexpr (EPI == EPI_FISTA) {
        __shared__ float red[TPB];
        red[tid] = loc; __syncthreads();
        for (int s = 128; s > 0; s >>= 1) { if (tid < s) red[tid] += red[tid + s]; __syncthreads(); }
        if (tid == 0) atomicAdd(&diffArr[iter], red[0]);
    }
}

// f32 [b][R][Cc] -> f16 [b][Cc][R]
__global__ __launch_bounds__(TPB) void tcvt(const float* __restrict__ in, long in_bs,
                                            f16* __restrict__ out, long out_bs, int R, int Cc) {
    __shared__ float t[32][33];
    const int b = blockIdx.z;
    const int r0 = blockIdx.y << 5, c0 = blockIdx.x << 5;
    const int tx = threadIdx.x & 31, ty = threadIdx.x >> 5;
    const float* ib = in + (long)b * in_bs;
    #pragma unroll
    for (int p = 0; p < 4; ++p) {
        const int r = ty + p * 8;
        t[r][tx] = ib[(long)(r0 + r) * Cc + c0 + tx];
    }
    __syncthreads();
    f16* ob = out + (long)b * out_bs;
    #pragma unroll
    for (int p = 0; p < 4; ++p) {
        const int c = ty + p * 8;
        ob[(long)(c0 + c) * R + r0 + tx] = (f16)t[tx][c];
    }
}

__global__ void cvt16(const float4* __restrict__ in, f16x4* __restrict__ out, long n4) {
    long i = (long)blockIdx.x * blockDim.x + threadIdx.x;
    const long st = (long)gridDim.x * blockDim.x;
    for (; i < n4; i += st) {
        const float4 v = in[i];
        f16x4 o; o.x = (f16)v.x; o.y = (f16)v.y; o.z = (f16)v.z; o.w = (f16)v.w;
        out[i] = o;
    }
}

// row softmax with the row staged in LDS
__global__ __launch_bounds__(TPB) void softmax_h(const float* __restrict__ Sf, f16* __restrict__ Sh) {
    __shared__ float row[HWD];
    __shared__ float red[TPB];
    const long base = (long)blockIdx.x * HWD;
    const int tid = threadIdx.x;
    float mx = -3.4e38f;
    for (int i = tid; i < HWD; i += TPB) { const float v = Sf[base + i]; row[i] = v; mx = fmaxf(mx, v); }
    red[tid] = mx; __syncthreads();
    for (int s = 128; s > 0; s >>= 1) { if (tid < s) red[tid] = fmaxf(red[tid], red[tid + s]); __syncthreads(); }
    mx = red[0]; __syncthreads();
    float sum = 0.f;
    for (int i = tid; i < HWD; i += TPB) { const float e = expf(row[i] - mx); row[i] = e; sum += e; }
    red[tid] = sum; __syncthreads();
    for (int s = 128; s > 0; s >>= 1) { if (tid < s) red[tid] += red[tid + s]; __syncthreads(); }
    const float inv = 1.0f / red[0];
    for (int i = tid; i < HWD; i += TPB) Sh[base + i] = (f16)(row[i] * inv);
}

// group-norm (256 groups of 9) + scale/shift -> x (fp16)
__global__ __launch_bounds__(TPB) void groupnorm_x(const float* __restrict__ contc,
                                                   const float* __restrict__ meanc,
                                                   const float* __restrict__ stdc,
                                                   f16* __restrict__ xh) {
    const long base = (long)blockIdx.x * HWD + (long)threadIdx.x * 9;
    float v[9];
    float mu = 0.f;
    #pragma unroll
    for (int j = 0; j < 9; ++j) { v[j] = contc[base + j]; mu += v[j]; }
    mu *= (1.0f / 9.0f);
    float var = 0.f;
    #pragma unroll
    for (int j = 0; j < 9; ++j) { const float d = v[j] - mu; var += d * d; }
    var *= (1.0f / 8.0f);
    const float rs = 1.0f / sqrtf(var + 1e-5f);
    #pragma unroll
    for (int j = 0; j < 9; ++j)
        xh[base + j] = (f16)((v[j] - mu) * rs * (float)stdc[base + j] + (float)meanc[base + j]);
}

// power-iteration matvec on fp16 matrix, input normalization folded in
__global__ __launch_bounds__(TPB) void matvec_h(const f16* __restrict__ Wm,
                                                const float* __restrict__ win,
                                                float* __restrict__ wout) {
    __shared__ float red[TPB];
    const int tid = threadIdx.x;
    float s = 0.f;
    for (int i = tid; i < HWD; i += TPB) { const float v = win[i]; s += v * v; }
    red[tid] = s; __syncthreads();
    for (int st = 128; st > 0; st >>= 1) { if (tid < st) red[tid] += red[tid + st]; __syncthreads(); }
    const float ninv = rsqrtf(red[0]);
    const int row = (blockIdx.x << 2) + (tid >> 6);
    const int lane = tid & 63;
    const f16x2* wr2 = (const f16x2*)(Wm + (long)row * HWD);
    float d = 0.f;
    for (int j = lane; j < HWD / 2; j += 64) {
        const f16x2 p = wr2[j];
        d += (float)p.x * win[2 * j] + (float)p.y * win[2 * j + 1];
    }
    #pragma unroll
    for (int o = 32; o > 0; o >>= 1) d += __shfl_down(d, o);
    if (lane == 0) wout[row] = d * ninv;
}

// L = (w . Wf w) / (w . w)
__global__ __launch_bounds__(TPB) void kernelL(const float* __restrict__ Wf,
                                               const float* __restrict__ w,
                                               float* __restrict__ Lnum, float* __restrict__ Lden) {
    __shared__ float red[TPB];
    const int tid = threadIdx.x;
    const int row = (blockIdx.x << 2) + (tid >> 6);
    const int lane = tid & 63;
    const float* wr = Wf + (long)row * HWD;
    float d = 0.f;
    for (int j = lane; j < HWD; j += 64) d += wr[j] * w[j];
    #pragma unroll
    for (int o = 32; o > 0; o >>= 1) d += __shfl_down(d, o);
    red[tid] = (lane == 0) ? d * w[row] : 0.f;
    __syncthreads();
    for (int s = 128; s > 0; s >>= 1) { if (tid < s) red[tid] += red[tid + s]; __syncthreads(); }
    if (tid == 0) atomicAdd(Lnum, red[0]);
    if (blockIdx.x == 0) {
        __syncthreads();
        float s2 = 0.f;
        for (int i = tid; i < HWD; i += TPB) { const float v = w[i]; s2 += v * v; }
        red[tid] = s2; __syncthreads();
        for (int s = 128; s > 0; s >>= 1) { if (tid < s) red[tid] += red[tid + s]; __syncthreads(); }
        if (tid == 0) *Lden = red[0];
    }
}

__global__ void lr_fin(const float* __restrict__ Lnum, const float* __restrict__ Lden,
                       float* __restrict__ lrs) {
    const float lr = Lden[0] / Lnum[0];
    lrs[0] = lr;
    lrs[1] = ALPHA * lr;
}

__global__ void init_small(float* __restrict__ wvec, float* __restrict__ diffArr,
                           float* __restrict__ Lnum) {
    const int tid = threadIdx.x;
    for (int i = tid; i < HWD; i += TPB) wvec[i] = (float)(1.0 / 48.0);
    if (tid < 43) diffArr[tid] = 0.f;
    if (tid == 64) Lnum[0] = 0.f;
}

__global__ void zero_kernel(float4* __restrict__ p, long n4) {
    long i = (long)blockIdx.x * blockDim.x + threadIdx.x;
    const long st = (long)gridDim.x * blockDim.x;
    for (; i < n4; i += st) p[i] = make_float4(0.f, 0.f, 0.f, 0.f);
}

// output copy: pick the z buffer holding the final iterate under done-freeze semantics.
__global__ void copy_fista(const float4* __restrict__ zfA, const float4* __restrict__ zfB,
                           float4* __restrict__ out, const float* __restrict__ diffArr, long n4) {
    int last = 42;
    for (int j = 0; j < 43; ++j) { if (diffArr[j] <= TOLF) { last = j; break; } }
    const float4* src = (last & 1) ? zfA : zfB;
    long i = (long)blockIdx.x * blockDim.x + threadIdx.x;
    const long st = (long)gridDim.x * blockDim.x;
    for (; i < n4; i += st) out[i] = src[i];
}

extern "C" void kernel_launch(void* const* d_in, const int* in_sizes, int n_in,
                              void* d_out, int out_size, void* d_ws, size_t ws_size,
                              hipStream_t stream) {
    (void)in_sizes; (void)n_in; (void)out_size;
    const float* content = (const float*)d_in[0];
    const float* style   = (const float*)d_in[1];
    const float* ckey    = (const float*)d_in[2];
    const float* skey    = (const float*)d_in[3];
    const float* f_w = (const float*)d_in[4];
    const float* f_b = (const float*)d_in[5];
    const float* g_w = (const float*)d_in[6];
    const float* g_b = (const float*)d_in[7];
    const float* h_w = (const float*)d_in[8];
    const float* h_b = (const float*)d_in[9];
    const float* Amat = (const float*)d_in[10];

    if (ws_size < 79500000) return;
    char* W = (char*)d_ws;

    const long E16 = (long)HWD * CDIM;          // 1,179,648
    const long EHH = (long)HWD * HWD;           // 5,308,416
    f16*  ckeyT = (f16*)(W + 0);
    f16*  skeyT = (f16*)(W + 4718592);
    f16*  styleT= (f16*)(W + 9437184);
    float* Sf   = (float*)(W + 0);
    f16*  Ah    = (f16*)(W + 0);
    f16*  At    = (f16*)(W + 10616832);
    f16*  Wh    = (f16*)(W + 21233664);
    f16*  W4h   = (f16*)(W + 31850496);
    f16*  W2h   = (f16*)(W + 0);
    float* contc= (float*)(W + 21233664);
    float* zfA  = (float*)(W + 0);
    float* zfB  = (float*)(W + 9437184);
    f16*  yh    = (f16*)(W + 31850496);
    f16*  Sh    = (f16*)(W + 42467328);
    float* meanc= (float*)(W + 42467328);
    float* stdc = (float*)(W + 42467328 + 9437184);
    float* Wf   = (float*)(W + 42467328);
    float* xAf  = (float*)(W + 42467328);
    f16*  Fh    = (f16*)(W + 63700992);
    f16*  Gh    = (f16*)(W + 63700992 + 4718592);
    f16*  Hh    = (f16*)(W + 63700992 + 9437184);
    f16*  meanx = (f16*)(W + 63700992);
    f16*  stdx  = (f16*)(W + 63700992 + 4718592);
    f16*  conth = (f16*)(W + 63700992 + 9437184);
    f16*  xh    = (f16*)(W + 63700992);
    float* w_a  = (float*)(W + 77856768);
    float* w_b  = (float*)(W + 77856768 + 9216);
    float* lrs  = (float*)(W + 77856768 + 18432);
    float* Lnum = (float*)(W + 77856768 + 18440);
    float* Lden = (float*)(W + 77856768 + 18444);
    float* diffArr = (float*)(W + 77856768 + 18448);
    f16*  fwh   = (f16*)(W + 77875712);
    f16*  gwh   = (f16*)(W + 77875712 + 524288);
    f16*  hwh   = (f16*)(W + 77875712 + 1048576);

    init_small<<<1, TPB, 0, stream>>>(w_a, diffArr, Lnum);

    cvt16<<<256, TPB, 0, stream>>>((const float4*)f_w, (f16x4*)fwh, (long)CDIM * CDIM / 4);
    cvt16<<<256, TPB, 0, stream>>>((const float4*)g_w, (f16x4*)gwh, (long)CDIM * CDIM / 4);
    cvt16<<<256, TPB, 0, stream>>>((const float4*)h_w, (f16x4*)hwh, (long)CDIM * CDIM / 4);
    tcvt<<<dim3(72, 16, 2), TPB, 0, stream>>>(ckey, E16, ckeyT, E16, CDIM, HWD);
    tcvt<<<dim3(72, 16, 2), TPB, 0, stream>>>(skey, E16, skeyT, E16, CDIM, HWD);
    tcvt<<<dim3(72, 16, 2), TPB, 0, stream>>>(style, E16, styleT, E16, CDIM, HWD);

    // convs (MF=1): F/G grids (8,72,2); H grid (36,16,2) — all 1152 blocks
    sgemm<EPI_F16BIASN, 1><<<dim3(8, 72, 2), TPB, 0, stream>>>(ckeyT, E16, CDIM, fwh, 0, CDIM,
        Fh, E16, CDIM, nullptr, CDIM, f_b, nullptr, nullptr, nullptr, nullptr, nullptr, 0.f, 0.f, nullptr, 0);
    sgemm<EPI_F16BIASN, 1><<<dim3(8, 72, 2), TPB, 0, stream>>>(skeyT, E16, CDIM, gwh, 0, CDIM,
        Gh, E16, CDIM, nullptr, CDIM, g_b, nullptr, nullptr, nullptr, nullptr, nullptr, 0.f, 0.f, nullptr, 0);
    sgemm<EPI_F16BIASM, 1><<<dim3(36, 16, 2), TPB, 0, stream>>>(hwh, 0, CDIM, styleT, E16, CDIM,
        Hh, E16, HWD, nullptr, CDIM, h_b, nullptr, nullptr, nullptr, nullptr, nullptr, 0.f, 0.f, nullptr, 0);

    // logits (MF=2, grid 2592) -> Sf f32 ; softmax -> Sh f16
    sgemm<EPI_F32, 2><<<dim3(36, 36, 2), TPB, 0, stream>>>(Fh, E16, CDIM, Gh, E16, CDIM,
        Sf, EHH, HWD, nullptr, CDIM, nullptr, nullptr, nullptr, nullptr, nullptr, nullptr, 0.f, 0.f, nullptr, 0);
    softmax_h<<<2 * HWD, TPB, 0, stream>>>(Sf, Sh);

    cvt16<<<2048, TPB, 0, stream>>>((const float4*)Amat, (f16x4*)Ah, EHH / 4);
    tcvt<<<dim3(72, 72, 1), TPB, 0, stream>>>(Amat, 0, At, 0, HWD, HWD);

    // mean/std (dual MFMA, MF=1, grid 1152)
    sgemm<EPI_MEANSTD, 1><<<dim3(8, 72, 2), TPB, 0, stream>>>(Sh, EHH, HWD, Hh, E16, HWD,
        meanx, 0, HWD, stdx, HWD, nullptr, nullptr, nullptr, nullptr, nullptr, nullptr, 0.f, 0.f, nullptr, 0);

    cvt16<<<2048, TPB, 0, stream>>>((const float4*)content, (f16x4*)conth, (long)2 * E16 / 4);

    // projections (MF=1, grid 1152)
    sgemm<EPI_F32, 1><<<dim3(36, 32, 1), TPB, 0, stream>>>(meanx, 0, HWD, Ah, 0, HWD,
        meanc, 0, HWD, nullptr, HWD, nullptr, nullptr, nullptr, nullptr, nullptr, nullptr, 0.f, 0.f, nullptr, 0);
    sgemm<EPI_F32, 1><<<dim3(36, 32, 1), TPB, 0, stream>>>(stdx, 0, HWD, Ah, 0, HWD,
        stdc, 0, HWD, nullptr, HWD, nullptr, nullptr, nullptr, nullptr, nullptr, nullptr, 0.f, 0.f, nullptr, 0);
    sgemm<EPI_F32, 1><<<dim3(36, 32, 1), TPB, 0, stream>>>(conth, 0, HWD, Ah, 0, HWD,
        contc, 0, HWD, nullptr, HWD, nullptr, nullptr, nullptr, nullptr, nullptr, nullptr, 0.f, 0.f, nullptr, 0);

    groupnorm_x<<<1024, TPB, 0, stream>>>(contc, meanc, stdc, xh);

    // WtW family (MF=2, grid 1296)
    sgemm<EPI_WTW, 2><<<dim3(36, 36, 1), TPB, 0, stream>>>(At, 0, HWD, At, 0, HWD,
        Wf, 0, HWD, Wh, HWD, nullptr, nullptr, nullptr, nullptr, nullptr, nullptr, 0.f, 0.f, nullptr, 0);
    sgemm<EPI_F16, 2><<<dim3(36, 36, 1), TPB, 0, stream>>>(Wh, 0, HWD, Wh, 0, HWD,
        W2h, 0, HWD, nullptr, HWD, nullptr, nullptr, nullptr, nullptr, nullptr, nullptr, 0.f, 0.f, nullptr, 0);
    sgemm<EPI_F16, 2><<<dim3(36, 36, 1), TPB, 0, stream>>>(W2h, 0, HWD, W2h, 0, HWD,
        W4h, 0, HWD, nullptr, HWD, nullptr, nullptr, nullptr, nullptr, nullptr, nullptr, 0.f, 0.f, nullptr, 0);

    for (int it = 0; it < 25; ++it) {
        const float* win = (it & 1) ? w_b : w_a;
        float* wout = (it & 1) ? w_a : w_b;
        matvec_h<<<HWD / 4, TPB, 0, stream>>>(W4h, win, wout);
    }
    kernelL<<<HWD / 4, TPB, 0, stream>>>(Wf, w_b, Lnum, Lden);
    lr_fin<<<1, 1, 0, stream>>>(Lnum, Lden, lrs);

    // xA (MF=1, grid 1152)
    sgemm<EPI_F32, 1><<<dim3(36, 32, 1), TPB, 0, stream>>>(xh, 0, HWD, At, 0, HWD,
        xAf, 0, HWD, nullptr, HWD, nullptr, nullptr, nullptr, nullptr, nullptr, nullptr, 0.f, 0.f, nullptr, 0);

    zero_kernel<<<1024, TPB, 0, stream>>>((float4*)zfA, E16);
    zero_kernel<<<1024, TPB, 0, stream>>>((float4*)yh, E16 / 4);

    // FISTA (MF=1, grid 1152): grad = y@WtW - xA; f32-y-recompute epilogue
    float t = 1.0f, coefPrev = 0.0f;
    for (int it = 0; it < 43; ++it) {
        const float tn = (1.0f + sqrtf(1.0f + 4.0f * t * t)) * 0.5f;
        const float coef = (t - 1.0f) / tn;
        t = tn;
        float* zc = (it & 1) ? zfB : zfA;
        float* zp = (it & 1) ? zfA : zfB;
        sgemm<EPI_FISTA, 1><<<dim3(36, 32, 1), TPB, 0, stream>>>(yh, 0, HWD, Wh, 0, HWD,
            nullptr, 0, HWD, nullptr, HWD, nullptr, xAf, zc, zp, yh, lrs, coefPrev, coef, diffArr, it);
        coefPrev = coef;
    }

    copy_fista<<<2048, TPB, 0, stream>>>((const float4*)zfA, (const float4*)zfB,
                                         (float4*)d_out, diffArr, 2 * E16 / 4);
}

// Round 14
// 2112.280 us; speedup vs baseline: 1.1470x; 1.1470x over previous
//
#include <hip/hip_runtime.h>
#include <hip/hip_cooperative_groups.h>
#include <math.h>

namespace cg = cooperative_groups;

#define TPB 256

typedef _Float16 f16;
typedef _Float16 half8 __attribute__((ext_vector_type(8)));
typedef _Float16 f16x2 __attribute__((ext_vector_type(2)));
typedef _Float16 f16x4 __attribute__((ext_vector_type(4)));
typedef float floatx4 __attribute__((ext_vector_type(4)));

static constexpr int CDIM = 512;
static constexpr int HWD = 2304;
static constexpr float ALPHA = 0.05f;
static constexpr float TOLF = 4.608e-4f;   // B*HW*1e-7

enum { EPI_F32 = 0, EPI_F16BIASN = 1, EPI_F16BIASM = 2, EPI_F16 = 3,
       EPI_WTW = 4, EPI_MEANSTD = 5 };

__device__ __forceinline__ bool fista_done(const float* __restrict__ diffArr, int iter) {
    bool done = false;
    for (int j = 0; j < iter; ++j) done = done || (diffArr[j] <= TOLF);
    return done;
}

// async global->LDS, 16B per lane (global_load_lds_dwordx4).
__device__ __forceinline__ void gload_lds(const f16* g, f16* l) {
#if __has_builtin(__builtin_amdgcn_global_load_lds)
    __builtin_amdgcn_global_load_lds(
        (__attribute__((address_space(1))) void*)(g),
        (__attribute__((address_space(3))) void*)(l), 16, 0, 0);
#else
    *(int4*)l = *(const int4*)g;
#endif
}

// counted vmcnt wait (T4)
template<int N> __device__ __forceinline__ void vwait() {
    if constexpr (N == 0)      asm volatile("s_waitcnt vmcnt(0)" ::: "memory");
    else if constexpr (N == 4) asm volatile("s_waitcnt vmcnt(4)" ::: "memory");
    else if constexpr (N == 6) asm volatile("s_waitcnt vmcnt(6)" ::: "memory");
}

// raw s_barrier with compiler memory fences
__device__ __forceinline__ void barrier_f() {
    asm volatile("" ::: "memory");
    __builtin_amdgcn_s_barrier();
    asm volatile("" ::: "memory");
}

// Generic fp16 MFMA GEMM (non-FISTA phases): C[m,n] = sum_k A[m][k]*B[n][k].
// Block (MF*32)x64, BK=64, 4 waves; NBUF=2 counted-vmcnt pipeline (R11-proven).
template<int EPI, int MF>
__global__ __launch_bounds__(TPB, 4) void sgemm(
    const f16* __restrict__ A, long a_bs, int lda,
    const f16* __restrict__ B, long b_bs, int ldb,
    void* __restrict__ C0, long c_bs, int ldc,
    void* __restrict__ C1,
    int K,
    const float* __restrict__ bias)
{
    constexpr int ASZ = MF * 32 * 64;
    constexpr int BSZ = 64 * 64;
    constexpr int LCNT = MF + 2;
    __shared__ alignas(16) f16 As[2 * ASZ];
    __shared__ alignas(16) f16 Bs[2 * BSZ];
    const int tid = threadIdx.x;
    const int wid = tid >> 6, lane = tid & 63;
    const int wr = wid >> 1, wc = wid & 1;

    const int gx = gridDim.x, gy = gridDim.y;
    const int nwg = gx * gy;
    const int d = blockIdx.y * gx + blockIdx.x;
    const int q = nwg >> 3, r = nwg & 7;
    const int xcd = d & 7, rest = d >> 3;
    const int wgid = (xcd < r ? xcd * (q + 1) : r * (q + 1) + (xcd - r) * q) + rest;
    const int bx = wgid / gy, by = wgid % gy;

    const int m0 = by * (MF * 32), n0 = bx << 6;
    const f16* Ab = A + (long)blockIdx.z * a_bs;
    const f16* Bb = B + (long)blockIdx.z * b_bs;

    floatx4 acc[MF][2] = {};
    floatx4 acc2[MF][2] = {};

    const int rl = lane & 15, kg = lane >> 4;
    const int lrow = lane >> 3;
    const int gs = (lane & 7) ^ lrow;
    const int nt = K >> 6;

    auto STAGE = [&](int t, int buf) {
        const long k0 = (long)t << 6;
        f16* Ad = As + buf * ASZ;
        f16* Bd = Bs + buf * BSZ;
        #pragma unroll
        for (int p = 0; p < MF; ++p) {
            const int c = wid * MF + p;
            const int R = c * 8 + lrow;
            gload_lds(Ab + (long)(m0 + R) * lda + k0 + gs * 8, Ad + c * 512);
        }
        #pragma unroll
        for (int p = 0; p < 2; ++p) {
            const int c = wid * 2 + p;
            const int R = c * 8 + lrow;
            gload_lds(Bb + (long)(n0 + R) * ldb + k0 + gs * 8, Bd + c * 512);
        }
    };

    STAGE(0, 0);
    for (int t = 0; t < nt; ++t) {
        if (t + 1 < nt) { STAGE(t + 1, (t + 1) & 1); vwait<LCNT>(); }
        else            { vwait<0>(); }
        barrier_f();
        const f16* Ac = As + (t & 1) * ASZ;
        const f16* Bc = Bs + (t & 1) * BSZ;
        #pragma unroll
        for (int kk = 0; kk < 2; ++kk) {
            const int j = kk * 4 + kg;
            half8 af[MF], bf[2];
            #pragma unroll
            for (int f = 0; f < MF; ++f) {
                const int rowa = wr * (MF * 16) + f * 16 + rl;
                af[f] = *(const half8*)&Ac[rowa * 64 + ((j ^ (rowa & 7)) * 8)];
            }
            #pragma unroll
            for (int f = 0; f < 2; ++f) {
                const int rowb = wc * 32 + f * 16 + rl;
                bf[f] = *(const half8*)&Bc[rowb * 64 + ((j ^ (rowb & 7)) * 8)];
            }
            #pragma unroll
            for (int fi = 0; fi < MF; ++fi) {
                #pragma unroll
                for (int fj = 0; fj < 2; ++fj) {
                    acc[fi][fj] = __builtin_amdgcn_mfma_f32_16x16x32_f16(af[fi], bf[fj], acc[fi][fj], 0, 0, 0);
                    if constexpr (EPI == EPI_MEANSTD) {
                        half8 bq = bf[fj] * bf[fj];
                        acc2[fi][fj] = __builtin_amdgcn_mfma_f32_16x16x32_f16(af[fi], bq, acc2[fi][fj], 0, 0, 0);
                    }
                }
            }
        }
        barrier_f();
    }

    const int rg = lane >> 4;
    const int bz = blockIdx.z;
    #pragma unroll
    for (int fi = 0; fi < MF; ++fi) {
        #pragma unroll
        for (int fj = 0; fj < 2; ++fj) {
            #pragma unroll
            for (int r2 = 0; r2 < 4; ++r2) {
                const int row = m0 + wr * (MF * 16) + fi * 16 + rg * 4 + r2;
                const int col = n0 + wc * 32 + fj * 16 + rl;
                const float v = acc[fi][fj][r2];
                if constexpr (EPI == EPI_F32) {
                    ((float*)C0)[bz * c_bs + (long)row * ldc + col] = v;
                } else if constexpr (EPI == EPI_F16BIASN) {
                    ((f16*)C0)[bz * c_bs + (long)row * ldc + col] = (f16)(v + bias[col]);
                } else if constexpr (EPI == EPI_F16BIASM) {
                    ((f16*)C0)[bz * c_bs + (long)row * ldc + col] = (f16)(v + bias[row]);
                } else if constexpr (EPI == EPI_F16) {
                    ((f16*)C0)[bz * c_bs + (long)row * ldc + col] = (f16)v;
                } else if constexpr (EPI == EPI_WTW) {
                    ((float*)C0)[(long)row * ldc + col] = v;
                    ((f16*)C1)[(long)row * ldc + col] = (f16)v;
                } else if constexpr (EPI == EPI_MEANSTD) {
                    const float m_ = v;
                    float s2 = acc2[fi][fj][r2] - m_ * m_;
                    const long o = ((long)bz * CDIM + col) * HWD + row;
                    ((f16*)C0)[o] = (f16)m_;
                    ((f16*)C1)[o] = (f16)sqrtf(s2 > 0.f ? s2 : 0.f);
                }
            }
        }
    }
}

// R14 coop: persistent FISTA, 288 blocks (128x64 tiles: 8 m x 36 n), MF=4.
// Even at 2 blocks/CU runtime occupancy, 512 >= 288 -> coop validation passes
// (R13's 576-block version was rejected: TooLarge, d_out never written).
// Per-thread register state across iterations: xa/z/y (32 f32 each).
// diffArr early-break read via AGENT-scope atomic load (no stale-L2 divergence).
__global__ __launch_bounds__(TPB, 2) void fista_coop(
    const f16* __restrict__ Wh,
    const float* __restrict__ xAf,
    f16* __restrict__ yA, f16* __restrict__ yB,
    const float* __restrict__ lrs,
    float* __restrict__ diffArr,
    float* __restrict__ dout)
{
    cg::grid_group grid = cg::this_grid();
    constexpr int MF = 4;
    constexpr int ASZ = MF * 32 * 64;
    constexpr int BSZ = 64 * 64;
    constexpr int LCNT = MF + 2;
    __shared__ alignas(16) f16 As[2 * ASZ];
    __shared__ alignas(16) f16 Bs[2 * BSZ];
    __shared__ float red[TPB];
    const int tid = threadIdx.x;
    const int wid = tid >> 6, lane = tid & 63;
    const int wr = wid >> 1, wc = wid & 1;

    // XCD swizzle over 288 blocks (288%8==0, q=36), y-fastest decode (8 m-tiles)
    const int d = blockIdx.x;
    const int wgid = (d & 7) * 36 + (d >> 3);
    const int bx = wgid >> 3, by = wgid & 7;
    const int m0 = by << 7, n0 = bx << 6;

    const int rl = lane & 15, kg = lane >> 4;
    const int rg = lane >> 4;
    const int lrow = lane >> 3;
    const int gs = (lane & 7) ^ lrow;
    constexpr int nt = HWD >> 6;   // 36

    const float lr = lrs[0], sh = lrs[1];

    float xar[MF][2][4], zr[MF][2][4], yr[MF][2][4];
    #pragma unroll
    for (int fi = 0; fi < MF; ++fi)
        #pragma unroll
        for (int fj = 0; fj < 2; ++fj)
            #pragma unroll
            for (int r2 = 0; r2 < 4; ++r2) {
                const int row = m0 + wr * (MF * 16) + fi * 16 + rg * 4 + r2;
                const int col = n0 + wc * 32 + fj * 16 + rl;
                xar[fi][fj][r2] = xAf[(long)row * HWD + col];
                zr[fi][fj][r2] = 0.f;
                yr[fi][fj][r2] = 0.f;
            }

    float t = 1.0f;
    for (int iter = 0; iter < 43; ++iter) {
        const float tn = (1.0f + sqrtf(1.0f + 4.0f * t * t)) * 0.5f;
        const float coef = (t - 1.0f) / tn;
        t = tn;
        const f16* Yin = (iter & 1) ? yB : yA;
        f16* Yout = (iter & 1) ? yA : yB;

        floatx4 acc[MF][2] = {};
        auto STAGE = [&](int tt, int buf) {
            const long k0 = (long)tt << 6;
            f16* Ad = As + buf * ASZ;
            f16* Bd = Bs + buf * BSZ;
            #pragma unroll
            for (int p = 0; p < MF; ++p) {
                const int c = wid * MF + p;
                const int R = c * 8 + lrow;
                gload_lds(Yin + (long)(m0 + R) * HWD + k0 + gs * 8, Ad + c * 512);
            }
            #pragma unroll
            for (int p = 0; p < 2; ++p) {
                const int c = wid * 2 + p;
                const int R = c * 8 + lrow;
                gload_lds(Wh + (long)(n0 + R) * HWD + k0 + gs * 8, Bd + c * 512);
            }
        };
        STAGE(0, 0);
        for (int tt = 0; tt < nt; ++tt) {
            if (tt + 1 < nt) { STAGE(tt + 1, (tt + 1) & 1); vwait<LCNT>(); }
            else             { vwait<0>(); }
            barrier_f();
            const f16* Ac = As + (tt & 1) * ASZ;
            const f16* Bc = Bs + (tt & 1) * BSZ;
            #pragma unroll
            for (int kk = 0; kk < 2; ++kk) {
                const int j = kk * 4 + kg;
                half8 af[MF], bf[2];
                #pragma unroll
                for (int f = 0; f < MF; ++f) {
                    const int rowa = wr * (MF * 16) + f * 16 + rl;
                    af[f] = *(const half8*)&Ac[rowa * 64 + ((j ^ (rowa & 7)) * 8)];
                }
                #pragma unroll
                for (int f = 0; f < 2; ++f) {
                    const int rowb = wc * 32 + f * 16 + rl;
                    bf[f] = *(const half8*)&Bc[rowb * 64 + ((j ^ (rowb & 7)) * 8)];
                }
                #pragma unroll
                for (int fi = 0; fi < MF; ++fi)
                    #pragma unroll
                    for (int fj = 0; fj < 2; ++fj)
                        acc[fi][fj] = __builtin_amdgcn_mfma_f32_16x16x32_f16(af[fi], bf[fj], acc[fi][fj], 0, 0, 0);
            }
            barrier_f();
        }

        float loc = 0.f;
        #pragma unroll
        for (int fi = 0; fi < MF; ++fi)
            #pragma unroll
            for (int fj = 0; fj < 2; ++fj)
                #pragma unroll
                for (int r2 = 0; r2 < 4; ++r2) {
                    const int row = m0 + wr * (MF * 16) + fi * 16 + rg * 4 + r2;
                    const int col = n0 + wc * 32 + fj * 16 + rl;
                    const float grad = acc[fi][fj][r2] - xar[fi][fj][r2];
                    const float p = yr[fi][fj][r2] - lr * grad;
                    const float ap = fabsf(p) - sh;
                    const float zn = ap > 0.f ? copysignf(ap, p) : 0.f;
                    const float zo = zr[fi][fj][r2];
                    loc += fabsf(zn - zo);
                    const float yn = zn + coef * (zn - zo);
                    zr[fi][fj][r2] = zn;
                    yr[fi][fj][r2] = yn;
                    Yout[(long)row * HWD + col] = (f16)yn;
                }
        red[tid] = loc; __syncthreads();
        for (int s = 128; s > 0; s >>= 1) { if (tid < s) red[tid] += red[tid + s]; __syncthreads(); }
        if (tid == 0) atomicAdd(&diffArr[iter], red[0]);

        __threadfence();       // release: publish y + diff
        grid.sync();
        __threadfence();       // acquire: see other XCDs' y + diff
        const float dsum = __hip_atomic_load(&diffArr[iter], __ATOMIC_RELAXED,
                                             __HIP_MEMORY_SCOPE_AGENT);
        if (dsum <= TOLF) break;   // uniform grid-wide (freeze semantics)
    }

    #pragma unroll
    for (int fi = 0; fi < MF; ++fi)
        #pragma unroll
        for (int fj = 0; fj < 2; ++fj)
            #pragma unroll
            for (int r2 = 0; r2 < 4; ++r2) {
                const int row = m0 + wr * (MF * 16) + fi * 16 + rg * 4 + r2;
                const int col = n0 + wc * 32 + fj * 16 + rl;
                dout[(long)row * HWD + col] = zr[fi][fj][r2];
            }
}

// R11-proven fallback FISTA step (MF=2, 576 blocks, counted vmcnt):
// grad = y@W - xA; f32 y recomputed from ping-ponged f32 z buffers.
__global__ __launch_bounds__(TPB, 3) void fista_step(
    const f16* __restrict__ Yin, const f16* __restrict__ Wh,
    const float* __restrict__ xAf,
    float* __restrict__ zc, float* __restrict__ zp, f16* __restrict__ yhp,
    const float* __restrict__ lrs, float coefPrev, float coefCur,
    float* __restrict__ diffArr, int iter)
{
    if (iter > 0 && fista_done(diffArr, iter)) return;
    constexpr int MF = 2;
    constexpr int ASZ = MF * 32 * 64;
    constexpr int BSZ = 64 * 64;
    constexpr int LCNT = MF + 2;
    __shared__ alignas(16) f16 As[2 * ASZ];
    __shared__ alignas(16) f16 Bs[2 * BSZ];
    __shared__ float red[TPB];
    const int tid = threadIdx.x;
    const int wid = tid >> 6, lane = tid & 63;
    const int wr = wid >> 1, wc = wid & 1;

    const int d = blockIdx.y * gridDim.x + blockIdx.x;
    const int wgid = (d & 7) * 72 + (d >> 3);   // 576 blocks, q=72
    const int bx = wgid >> 4, by = wgid & 15;
    const int m0 = by << 6, n0 = bx << 6;

    floatx4 acc[MF][2] = {};
    const int rl = lane & 15, kg = lane >> 4;
    const int lrow = lane >> 3;
    const int gs = (lane & 7) ^ lrow;
    constexpr int nt = HWD >> 6;

    auto STAGE = [&](int t, int buf) {
        const long k0 = (long)t << 6;
        f16* Ad = As + buf * ASZ;
        f16* Bd = Bs + buf * BSZ;
        #pragma unroll
        for (int p = 0; p < MF; ++p) {
            const int c = wid * MF + p;
            const int R = c * 8 + lrow;
            gload_lds(Yin + (long)(m0 + R) * HWD + k0 + gs * 8, Ad + c * 512);
        }
        #pragma unroll
        for (int p = 0; p < 2; ++p) {
            const int c = wid * 2 + p;
            const int R = c * 8 + lrow;
            gload_lds(Wh + (long)(n0 + R) * HWD + k0 + gs * 8, Bd + c * 512);
        }
    };
    STAGE(0, 0);
    for (int t = 0; t < nt; ++t) {
        if (t + 1 < nt) { STAGE(t + 1, (t + 1) & 1); vwait<LCNT>(); }
        else            { vwait<0>(); }
        barrier_f();
        const f16* Ac = As + (t & 1) * ASZ;
        const f16* Bc = Bs + (t & 1) * BSZ;
        #pragma unroll
        for (int kk = 0; kk < 2; ++kk) {
            const int j = kk * 4 + kg;
            half8 af[MF], bf[2];
            #pragma unroll
            for (int f = 0; f < MF; ++f) {
                const int rowa = wr * (MF * 16) + f * 16 + rl;
                af[f] = *(const half8*)&Ac[rowa * 64 + ((j ^ (rowa & 7)) * 8)];
            }
            #pragma unroll
            for (int f = 0; f < 2; ++f) {
                const int rowb = wc * 32 + f * 16 + rl;
                bf[f] = *(const half8*)&Bc[rowb * 64 + ((j ^ (rowb & 7)) * 8)];
            }
            #pragma unroll
            for (int fi = 0; fi < MF; ++fi)
                #pragma unroll
                for (int fj = 0; fj < 2; ++fj)
                    acc[fi][fj] = __builtin_amdgcn_mfma_f32_16x16x32_f16(af[fi], bf[fj], acc[fi][fj], 0, 0, 0);
        }
        barrier_f();
    }

    const int rg = lane >> 4;
    const float lr = lrs[0], sh = lrs[1];
    float loc = 0.f;
    #pragma unroll
    for (int fi = 0; fi < MF; ++fi)
        #pragma unroll
        for (int fj = 0; fj < 2; ++fj)
            #pragma unroll
            for (int r2 = 0; r2 < 4; ++r2) {
                const int row = m0 + wr * (MF * 16) + fi * 16 + rg * 4 + r2;
                const int col = n0 + wc * 32 + fj * 16 + rl;
                const long off = (long)row * HWD + col;
                const float zk = zc[off];
                const float zkm = zp[off];
                const float ykf = zk + coefPrev * (zk - zkm);
                const float grad = acc[fi][fj][r2] - xAf[off];
                const float p = ykf - lr * grad;
                const float ap = fabsf(p) - sh;
                const float zn = ap > 0.f ? copysignf(ap, p) : 0.f;
                zp[off] = zn;
                yhp[off] = (f16)(zn + coefCur * (zn - zk));
                loc += fabsf(zn - zk);
            }
    red[tid] = loc; __syncthreads();
    for (int s = 128; s > 0; s >>= 1) { if (tid < s) red[tid] += red[tid + s]; __syncthreads(); }
    if (tid == 0) atomicAdd(&diffArr[iter], red[0]);
}

// f32 [b][R][Cc] -> f16 [b][Cc][R]
__global__ __launch_bounds__(TPB) void tcvt(const float* __restrict__ in, long in_bs,
                                            f16* __restrict__ out, long out_bs, int R, int Cc) {
    __shared__ float t[32][33];
    const int b = blockIdx.z;
    const int r0 = blockIdx.y << 5, c0 = blockIdx.x << 5;
    const int tx = threadIdx.x & 31, ty = threadIdx.x >> 5;
    const float* ib = in + (long)b * in_bs;
    #pragma unroll
    for (int p = 0; p < 4; ++p) {
        const int r = ty + p * 8;
        t[r][tx] = ib[(long)(r0 + r) * Cc + c0 + tx];
    }
    __syncthreads();
    f16* ob = out + (long)b * out_bs;
    #pragma unroll
    for (int p = 0; p < 4; ++p) {
        const int c = ty + p * 8;
        ob[(long)(c0 + c) * R + r0 + tx] = (f16)t[tx][c];
    }
}

__global__ void cvt16(const float4* __restrict__ in, f16x4* __restrict__ out, long n4) {
    long i = (long)blockIdx.x * blockDim.x + threadIdx.x;
    const long st = (long)gridDim.x * blockDim.x;
    for (; i < n4; i += st) {
        const float4 v = in[i];
        f16x4 o; o.x = (f16)v.x; o.y = (f16)v.y; o.z = (f16)v.z; o.w = (f16)v.w;
        out[i] = o;
    }
}

__global__ __launch_bounds__(TPB) void softmax_h(const float* __restrict__ Sf, f16* __restrict__ Sh) {
    __shared__ float row[HWD];
    __shared__ float red[TPB];
    const long base = (long)blockIdx.x * HWD;
    const int tid = threadIdx.x;
    float mx = -3.4e38f;
    for (int i = tid; i < HWD; i += TPB) { const float v = Sf[base + i]; row[i] = v; mx = fmaxf(mx, v); }
    red[tid] = mx; __syncthreads();
    for (int s = 128; s > 0; s >>= 1) { if (tid < s) red[tid] = fmaxf(red[tid], red[tid + s]); __syncthreads(); }
    mx = red[0]; __syncthreads();
    float sum = 0.f;
    for (int i = tid; i < HWD; i += TPB) { const float e = expf(row[i] - mx); row[i] = e; sum += e; }
    red[tid] = sum; __syncthreads();
    for (int s = 128; s > 0; s >>= 1) { if (tid < s) red[tid] += red[tid + s]; __syncthreads(); }
    const float inv = 1.0f / red[0];
    for (int i = tid; i < HWD; i += TPB) Sh[base + i] = (f16)(row[i] * inv);
}

__global__ __launch_bounds__(TPB) void groupnorm_x(const float* __restrict__ contc,
                                                   const float* __restrict__ meanc,
                                                   const float* __restrict__ stdc,
                                                   f16* __restrict__ xh) {
    const long base = (long)blockIdx.x * HWD + (long)threadIdx.x * 9;
    float v[9];
    float mu = 0.f;
    #pragma unroll
    for (int j = 0; j < 9; ++j) { v[j] = contc[base + j]; mu += v[j]; }
    mu *= (1.0f / 9.0f);
    float var = 0.f;
    #pragma unroll
    for (int j = 0; j < 9; ++j) { const float d = v[j] - mu; var += d * d; }
    var *= (1.0f / 8.0f);
    const float rs = 1.0f / sqrtf(var + 1e-5f);
    #pragma unroll
    for (int j = 0; j < 9; ++j)
        xh[base + j] = (f16)((v[j] - mu) * rs * (float)stdc[base + j] + (float)meanc[base + j]);
}

__global__ __launch_bounds__(TPB) void matvec_h(const f16* __restrict__ Wm,
                                                const float* __restrict__ win,
                                                float* __restrict__ wout) {
    __shared__ float red[TPB];
    const int tid = threadIdx.x;
    float s = 0.f;
    for (int i = tid; i < HWD; i += TPB) { const float v = win[i]; s += v * v; }
    red[tid] = s; __syncthreads();
    for (int st = 128; st > 0; st >>= 1) { if (tid < st) red[tid] += red[tid + st]; __syncthreads(); }
    const float ninv = rsqrtf(red[0]);
    const int row = (blockIdx.x << 2) + (tid >> 6);
    const int lane = tid & 63;
    const f16x2* wr2 = (const f16x2*)(Wm + (long)row * HWD);
    float d = 0.f;
    for (int j = lane; j < HWD / 2; j += 64) {
        const f16x2 p = wr2[j];
        d += (float)p.x * win[2 * j] + (float)p.y * win[2 * j + 1];
    }
    #pragma unroll
    for (int o = 32; o > 0; o >>= 1) d += __shfl_down(d, o);
    if (lane == 0) wout[row] = d * ninv;
}

__global__ __launch_bounds__(TPB) void kernelL(const float* __restrict__ Wf,
                                               const float* __restrict__ w,
                                               float* __restrict__ Lnum, float* __restrict__ Lden) {
    __shared__ float red[TPB];
    const int tid = threadIdx.x;
    const int row = (blockIdx.x << 2) + (tid >> 6);
    const int lane = tid & 63;
    const float* wr = Wf + (long)row * HWD;
    float d = 0.f;
    for (int j = lane; j < HWD; j += 64) d += wr[j] * w[j];
    #pragma unroll
    for (int o = 32; o > 0; o >>= 1) d += __shfl_down(d, o);
    red[tid] = (lane == 0) ? d * w[row] : 0.f;
    __syncthreads();
    for (int s = 128; s > 0; s >>= 1) { if (tid < s) red[tid] += red[tid + s]; __syncthreads(); }
    if (tid == 0) atomicAdd(Lnum, red[0]);
    if (blockIdx.x == 0) {
        __syncthreads();
        float s2 = 0.f;
        for (int i = tid; i < HWD; i += TPB) { const float v = w[i]; s2 += v * v; }
        red[tid] = s2; __syncthreads();
        for (int s = 128; s > 0; s >>= 1) { if (tid < s) red[tid] += red[tid + s]; __syncthreads(); }
        if (tid == 0) *Lden = red[0];
    }
}

__global__ void lr_fin(const float* __restrict__ Lnum, const float* __restrict__ Lden,
                       float* __restrict__ lrs) {
    const float lr = Lden[0] / Lnum[0];
    lrs[0] = lr;
    lrs[1] = ALPHA * lr;
}

__global__ void init_small(float* __restrict__ wvec, float* __restrict__ diffArr,
                           float* __restrict__ Lnum) {
    const int tid = threadIdx.x;
    for (int i = tid; i < HWD; i += TPB) wvec[i] = (float)(1.0 / 48.0);
    if (tid < 43) diffArr[tid] = 0.f;
    if (tid == 64) Lnum[0] = 0.f;
}

__global__ void zero_kernel(float4* __restrict__ p, long n4) {
    long i = (long)blockIdx.x * blockDim.x + threadIdx.x;
    const long st = (long)gridDim.x * blockDim.x;
    for (; i < n4; i += st) p[i] = make_float4(0.f, 0.f, 0.f, 0.f);
}

// fallback output copy: pick the z buffer with the final iterate under freeze semantics.
__global__ void copy_fista(const float4* __restrict__ zfA, const float4* __restrict__ zfB,
                           float4* __restrict__ out, const float* __restrict__ diffArr, long n4) {
    int last = 42;
    for (int j = 0; j < 43; ++j) { if (diffArr[j] <= TOLF) { last = j; break; } }
    const float4* src = (last & 1) ? zfA : zfB;
    long i = (long)blockIdx.x * blockDim.x + threadIdx.x;
    const long st = (long)gridDim.x * blockDim.x;
    for (; i < n4; i += st) out[i] = src[i];
}

extern "C" void kernel_launch(void* const* d_in, const int* in_sizes, int n_in,
                              void* d_out, int out_size, void* d_ws, size_t ws_size,
                              hipStream_t stream) {
    (void)in_sizes; (void)n_in; (void)out_size;
    const float* content = (const float*)d_in[0];
    const float* style   = (const float*)d_in[1];
    const float* ckey    = (const float*)d_in[2];
    const float* skey    = (const float*)d_in[3];
    const float* f_w = (const float*)d_in[4];
    const float* f_b = (const float*)d_in[5];
    const float* g_w = (const float*)d_in[6];
    const float* g_b = (const float*)d_in[7];
    const float* h_w = (const float*)d_in[8];
    const float* h_b = (const float*)d_in[9];
    const float* Amat = (const float*)d_in[10];

    if (ws_size < 79500000) return;
    char* W = (char*)d_ws;

    const long E16 = (long)HWD * CDIM;          // 1,179,648
    const long EHH = (long)HWD * HWD;           // 5,308,416
    f16*  ckeyT = (f16*)(W + 0);
    f16*  skeyT = (f16*)(W + 4718592);
    f16*  styleT= (f16*)(W + 9437184);
    float* Sf   = (float*)(W + 0);
    f16*  Ah    = (f16*)(W + 0);
    f16*  At    = (f16*)(W + 10616832);
    f16*  Wh    = (f16*)(W + 21233664);
    f16*  W4h   = (f16*)(W + 31850496);
    f16*  W2h   = (f16*)(W + 0);
    float* contc= (float*)(W + 21233664);
    float* zfA  = (float*)(W + 0);              // fallback z ping A
    float* zfB  = (float*)(W + 9437184);        // fallback z ping B
    f16*  yhA   = (f16*)(W + 31850496);         // y ping A (in dead W4h region)
    f16*  yhB   = (f16*)(W + 36569088);         // y ping B (also in dead W4h region)
    f16*  Sh    = (f16*)(W + 42467328);
    float* meanc= (float*)(W + 42467328);
    float* stdc = (float*)(W + 42467328 + 9437184);
    float* Wf   = (float*)(W + 42467328);
    float* xAf  = (float*)(W + 42467328);
    f16*  Fh    = (f16*)(W + 63700992);
    f16*  Gh    = (f16*)(W + 63700992 + 4718592);
    f16*  Hh    = (f16*)(W + 63700992 + 9437184);
    f16*  meanx = (f16*)(W + 63700992);
    f16*  stdx  = (f16*)(W + 63700992 + 4718592);
    f16*  conth = (f16*)(W + 63700992 + 9437184);
    f16*  xh    = (f16*)(W + 63700992);
    float* w_a  = (float*)(W + 77856768);
    float* w_b  = (float*)(W + 77856768 + 9216);
    float* lrs  = (float*)(W + 77856768 + 18432);
    float* Lnum = (float*)(W + 77856768 + 18440);
    float* Lden = (float*)(W + 77856768 + 18444);
    float* diffArr = (float*)(W + 77856768 + 18448);
    f16*  fwh   = (f16*)(W + 77875712);
    f16*  gwh   = (f16*)(W + 77875712 + 524288);
    f16*  hwh   = (f16*)(W + 77875712 + 1048576);

    init_small<<<1, TPB, 0, stream>>>(w_a, diffArr, Lnum);

    cvt16<<<256, TPB, 0, stream>>>((const float4*)f_w, (f16x4*)fwh, (long)CDIM * CDIM / 4);
    cvt16<<<256, TPB, 0, stream>>>((const float4*)g_w, (f16x4*)gwh, (long)CDIM * CDIM / 4);
    cvt16<<<256, TPB, 0, stream>>>((const float4*)h_w, (f16x4*)hwh, (long)CDIM * CDIM / 4);
    tcvt<<<dim3(72, 16, 2), TPB, 0, stream>>>(ckey, E16, ckeyT, E16, CDIM, HWD);
    tcvt<<<dim3(72, 16, 2), TPB, 0, stream>>>(skey, E16, skeyT, E16, CDIM, HWD);
    tcvt<<<dim3(72, 16, 2), TPB, 0, stream>>>(style, E16, styleT, E16, CDIM, HWD);

    sgemm<EPI_F16BIASN, 2><<<dim3(8, 36, 2), TPB, 0, stream>>>(ckeyT, E16, CDIM, fwh, 0, CDIM,
        Fh, E16, CDIM, nullptr, CDIM, f_b);
    sgemm<EPI_F16BIASN, 2><<<dim3(8, 36, 2), TPB, 0, stream>>>(skeyT, E16, CDIM, gwh, 0, CDIM,
        Gh, E16, CDIM, nullptr, CDIM, g_b);
    sgemm<EPI_F16BIASM, 2><<<dim3(36, 8, 2), TPB, 0, stream>>>(hwh, 0, CDIM, styleT, E16, CDIM,
        Hh, E16, HWD, nullptr, CDIM, h_b);

    sgemm<EPI_F32, 2><<<dim3(36, 36, 2), TPB, 0, stream>>>(Fh, E16, CDIM, Gh, E16, CDIM,
        Sf, EHH, HWD, nullptr, CDIM, nullptr);
    softmax_h<<<2 * HWD, TPB, 0, stream>>>(Sf, Sh);

    cvt16<<<2048, TPB, 0, stream>>>((const float4*)Amat, (f16x4*)Ah, EHH / 4);
    tcvt<<<dim3(72, 72, 1), TPB, 0, stream>>>(Amat, 0, At, 0, HWD, HWD);

    sgemm<EPI_MEANSTD, 2><<<dim3(8, 36, 2), TPB, 0, stream>>>(Sh, EHH, HWD, Hh, E16, HWD,
        meanx, 0, HWD, stdx, HWD, nullptr);

    cvt16<<<2048, TPB, 0, stream>>>((const float4*)content, (f16x4*)conth, (long)2 * E16 / 4);

    sgemm<EPI_F32, 2><<<dim3(36, 16, 1), TPB, 0, stream>>>(meanx, 0, HWD, Ah, 0, HWD,
        meanc, 0, HWD, nullptr, HWD, nullptr);
    sgemm<EPI_F32, 2><<<dim3(36, 16, 1), TPB, 0, stream>>>(stdx, 0, HWD, Ah, 0, HWD,
        stdc, 0, HWD, nullptr, HWD, nullptr);
    sgemm<EPI_F32, 2><<<dim3(36, 16, 1), TPB, 0, stream>>>(conth, 0, HWD, Ah, 0, HWD,
        contc, 0, HWD, nullptr, HWD, nullptr);

    groupnorm_x<<<1024, TPB, 0, stream>>>(contc, meanc, stdc, xh);

    sgemm<EPI_WTW, 2><<<dim3(36, 36, 1), TPB, 0, stream>>>(At, 0, HWD, At, 0, HWD,
        Wf, 0, HWD, Wh, HWD, nullptr);
    sgemm<EPI_F16, 2><<<dim3(36, 36, 1), TPB, 0, stream>>>(Wh, 0, HWD, Wh, 0, HWD,
        W2h, 0, HWD, nullptr, HWD, nullptr);
    sgemm<EPI_F16, 2><<<dim3(36, 36, 1), TPB, 0, stream>>>(W2h, 0, HWD, W2h, 0, HWD,
        W4h, 0, HWD, nullptr, HWD, nullptr);

    for (int it = 0; it < 25; ++it) {
        const float* win = (it & 1) ? w_b : w_a;
        float* wout = (it & 1) ? w_a : w_b;
        matvec_h<<<HWD / 4, TPB, 0, stream>>>(W4h, win, wout);
    }
    kernelL<<<HWD / 4, TPB, 0, stream>>>(Wf, w_b, Lnum, Lden);
    lr_fin<<<1, 1, 0, stream>>>(Lnum, Lden, lrs);

    sgemm<EPI_F32, 2><<<dim3(36, 16, 1), TPB, 0, stream>>>(xh, 0, HWD, At, 0, HWD,
        xAf, 0, HWD, nullptr, HWD, nullptr);

    // ---- FISTA: cooperative persistent if runtime validates capacity; else 43 dispatches ----
    int dev = 0; hipGetDevice(&dev);
    int coopOK = 0, numCU = 0, maxB = 0;
    hipDeviceGetAttribute(&coopOK, hipDeviceAttributeCooperativeLaunch, dev);
    hipDeviceGetAttribute(&numCU, hipDeviceAttributeMultiprocessorCount, dev);
    hipOccupancyMaxActiveBlocksPerMultiprocessor(&maxB, fista_coop, TPB, 0);
    const bool useCoop = coopOK && ((long)maxB * numCU >= 288);

    zero_kernel<<<1024, TPB, 0, stream>>>((float4*)yhA, E16 / 4);   // y_0 = 0

    if (useCoop) {
        float* doutF = (float*)d_out;
        void* args[] = { (void*)&Wh, (void*)&xAf, (void*)&yhA, (void*)&yhB,
                         (void*)&lrs, (void*)&diffArr, (void*)&doutF };
        hipLaunchCooperativeKernel((const void*)fista_coop, dim3(288), dim3(TPB),
                                   args, 0, stream);
    } else {
        // fallback: R11-proven 43-dispatch loop with f32 z ping-pong
        zero_kernel<<<1024, TPB, 0, stream>>>((float4*)zfA, E16);   // zfA+zfB contiguous
        float t = 1.0f, coefPrev = 0.0f;
        for (int it = 0; it < 43; ++it) {
            const float tn = (1.0f + sqrtf(1.0f + 4.0f * t * t)) * 0.5f;
            const float coef = (t - 1.0f) / tn;
            t = tn;
            float* zc = (it & 1) ? zfB : zfA;
            float* zp = (it & 1) ? zfA : zfB;
            fista_step<<<dim3(36, 16, 1), TPB, 0, stream>>>(yhA, Wh, xAf, zc, zp, yhA,
                                                            lrs, coefPrev, coef, diffArr, it);
            coefPrev = coef;
        }
        copy_fista<<<2048, TPB, 0, stream>>>((const float4*)zfA, (const float4*)zfB,
                                             (float4*)d_out, diffArr, 2 * E16 / 4);
    }
}